// Round 2
// baseline (1087.621 us; speedup 1.0000x reference)
//
#include <hip/hip_runtime.h>
#include <hip/hip_bf16.h>
#include <stdint.h>

#define NN   4096
#define HIDN 256
#define NHD  8
#define HD   32

typedef __attribute__((ext_vector_type(8))) short short8;
typedef __attribute__((ext_vector_type(4))) float f32x4;

static __device__ __forceinline__ unsigned short f2bf(float f) {
  __hip_bfloat16 h = __float2bfloat16(f);
  return __builtin_bit_cast(unsigned short, h);
}
static __device__ __forceinline__ float bf2f(unsigned short u) {
  __hip_bfloat16 h = __builtin_bit_cast(__hip_bfloat16, u);
  return __bfloat162float(h);
}

// ---------------------------------------------------------------------------
// Kernel 1: Q = (x@Wq^T + bq) * (log2e/sqrt(32)) ; V = x@Wv^T + bv
// Written as bf16 hi/lo splits (row-major [N][256]) + single-bf16 V^T [256][N].
// fp32 vector FMA; x loads are block-uniform (scalar path), W rows per-thread.
// ---------------------------------------------------------------------------
__global__ __launch_bounds__(256) void mhg_qv_kernel(
    const float* __restrict__ x,
    const float* __restrict__ wq_w, const float* __restrict__ wq_b,
    const float* __restrict__ wv_w, const float* __restrict__ wv_b,
    unsigned short* __restrict__ Qhi, unsigned short* __restrict__ Qlo,
    unsigned short* __restrict__ Vhi, unsigned short* __restrict__ Vlo,
    unsigned short* __restrict__ Vt)
{
  const int o  = threadIdx.x;        // output column 0..255
  const int r0 = blockIdx.x * 8;     // 8 rows per block
  float aq[8], av[8];
#pragma unroll
  for (int r = 0; r < 8; ++r) { aq[r] = 0.f; av[r] = 0.f; }
  const float4* wq4 = (const float4*)(wq_w + (size_t)o * HIDN);
  const float4* wv4 = (const float4*)(wv_w + (size_t)o * HIDN);
  const float* xb = x + (size_t)r0 * HIDN;
  for (int k0 = 0; k0 < HIDN / 4; ++k0) {
    float4 wq = wq4[k0];
    float4 wv = wv4[k0];
#pragma unroll
    for (int r = 0; r < 8; ++r) {
      float4 xv = *(const float4*)(xb + r * HIDN + k0 * 4);
      aq[r] = fmaf(xv.x, wq.x, fmaf(xv.y, wq.y, fmaf(xv.z, wq.z, fmaf(xv.w, wq.w, aq[r]))));
      av[r] = fmaf(xv.x, wv.x, fmaf(xv.y, wv.y, fmaf(xv.z, wv.z, fmaf(xv.w, wv.w, av[r]))));
    }
  }
  const float bq = wq_b[o], bv = wv_b[o];
  constexpr float CS = (float)(1.4426950408889634 / 5.656854249492380195206754896838);
  alignas(16) unsigned short vt8[8];
#pragma unroll
  for (int r = 0; r < 8; ++r) {
    float qv = (aq[r] + bq) * CS;             // prescale: exp(s/sqrt(32)) == exp2(q_scaled . v)
    unsigned short qh = f2bf(qv);
    unsigned short ql = f2bf(qv - bf2f(qh));  // 2-term split: ~2^-17 relative
    float vv = av[r] + bv;
    unsigned short vh = f2bf(vv);
    unsigned short vl = f2bf(vv - bf2f(vh));
    size_t idx = (size_t)(r0 + r) * HIDN + o;
    Qhi[idx] = qh; Qlo[idx] = ql;
    Vhi[idx] = vh; Vlo[idx] = vl;
    vt8[r] = vh;                              // thread already owns column o of all 8 rows
  }
  *(uint4*)(Vt + (size_t)o * NN + r0) = *(const uint4*)vt8;  // V^T, 16B coalesced-ish store
}

// ---------------------------------------------------------------------------
// Kernel 2: fused scores -> softmax -> attn write + O accumulate.
// 4 waves (256 thr) per (head, 16-row group); wave wv owns column-chunks
// [64*wv, 64*wv+64). Pass-A l partials reduced across waves via Lpart LDS;
// pass-B O partials reduced via Opart LDS. Occupancy 8 waves/SIMD.
// attn stores are PLAIN stores (round-1 post-mortem: nontemporal stores
// defeated L2 write-merging -> WRITE_SIZE x1.54, and serialized the V-load
// vmcnt waits behind HBM store drain -> every pipe stalled).
// Adjacency mask held as per-lane uint64 bitmask registers (1 bit per local
// chunk) -- each lane only ever tests its own Adj element in pass B.
// MFMA 16x16x32 bf16, K=32=head dim; hi/lo split for ~2^-17 precision.
// ---------------------------------------------------------------------------
__global__ __launch_bounds__(256, 8) void mhg_attn_kernel(
    const int* __restrict__ Adj,
    const unsigned short* __restrict__ Qhi, const unsigned short* __restrict__ Qlo,
    const unsigned short* __restrict__ Vhi, const unsigned short* __restrict__ Vlo,
    const unsigned short* __restrict__ Vt,
    float* __restrict__ attn, float* __restrict__ O)
{
  const int tid  = threadIdx.x;
  const int lane = tid & 63;
  const int wv   = tid >> 6;         // wave 0..3
  const int n    = lane & 15;        // tile column (and A-frag row m)
  const int qd   = lane >> 4;        // quad
  const int h    = blockIdx.x & (NHD - 1);   // head -> XCD-affine (bx % 8)
  const int rb   = blockIdx.x >> 3;
  const int wr0  = rb * 16;

  __shared__ __align__(16) unsigned short Plds[4][16][40];  // per-wave P tile, +8 pad
  __shared__ float Lpart[4][16];                            // per-wave row-sum partials
  __shared__ float Opart[4][16][33];                        // per-wave O partials (+1 pad)

  const size_t hoff = (size_t)h * HD + qd * 8;
  const short8 a_hi = *(const short8*)(Qhi + (size_t)(wr0 + n) * HIDN + hoff);
  const short8 a_lo = *(const short8*)(Qlo + (size_t)(wr0 + n) * HIDN + hoff);
  const unsigned short* pVh = Vhi + (size_t)n * HIDN + hoff;
  const unsigned short* pVl = Vlo + (size_t)n * HIDN + hoff;
  const size_t adjb = (size_t)(wr0 + 4 * qd) * NN + n;

  const int c0w = wv * 64;           // this wave's chunk range [c0w, c0w+64)

  float l0 = 0.f, l1 = 0.f, l2 = 0.f, l3 = 0.f;
  uint64_t m0 = 0, m1 = 0, m2 = 0, m3 = 0;   // per-lane mask bits, 1 bit/local chunk

  // ---- pass A (software-pipelined one chunk ahead) ----
  short8 bh = *(const short8*)(pVh + (size_t)c0w * (16 * HIDN));
  short8 bl = *(const short8*)(pVl + (size_t)c0w * (16 * HIDN));
  size_t ab0 = adjb + (size_t)c0w * 16;
  int a0 = Adj[ab0], a1 = Adj[ab0 + NN], a2 = Adj[ab0 + 2 * NN], a3 = Adj[ab0 + 3 * NN];

  for (int cc = 0; cc < 64; ++cc) {
    const int cn = c0w + ((cc < 63) ? cc + 1 : 63);
    short8 bhn = *(const short8*)(pVh + (size_t)cn * (16 * HIDN));
    short8 bln = *(const short8*)(pVl + (size_t)cn * (16 * HIDN));
    const size_t ab = adjb + (size_t)cn * 16;
    int a0n = Adj[ab], a1n = Adj[ab + NN], a2n = Adj[ab + 2 * NN], a3n = Adj[ab + 3 * NN];

    f32x4 acc = {0.f, 0.f, 0.f, 0.f};
    acc = __builtin_amdgcn_mfma_f32_16x16x32_bf16(a_hi, bh, acc, 0, 0, 0);
    acc = __builtin_amdgcn_mfma_f32_16x16x32_bf16(a_lo, bh, acc, 0, 0, 0);
    acc = __builtin_amdgcn_mfma_f32_16x16x32_bf16(a_hi, bl, acc, 0, 0, 0);

    m0 |= (uint64_t)(a0 != 0) << cc;
    m1 |= (uint64_t)(a1 != 0) << cc;
    m2 |= (uint64_t)(a2 != 0) << cc;
    m3 |= (uint64_t)(a3 != 0) << cc;

    l0 += a0 ? __builtin_amdgcn_exp2f(acc[0]) : 0.f;
    l1 += a1 ? __builtin_amdgcn_exp2f(acc[1]) : 0.f;
    l2 += a2 ? __builtin_amdgcn_exp2f(acc[2]) : 0.f;
    l3 += a3 ? __builtin_amdgcn_exp2f(acc[3]) : 0.f;

    bh = bhn; bl = bln; a0 = a0n; a1 = a1n; a2 = a2n; a3 = a3n;
  }

  // quad-local butterfly (width 16), then cross-wave sum via LDS
  {
    float s;
    s = l0; s += __shfl_xor(s, 1, 16); s += __shfl_xor(s, 2, 16); s += __shfl_xor(s, 4, 16); s += __shfl_xor(s, 8, 16); l0 = s;
    s = l1; s += __shfl_xor(s, 1, 16); s += __shfl_xor(s, 2, 16); s += __shfl_xor(s, 4, 16); s += __shfl_xor(s, 8, 16); l1 = s;
    s = l2; s += __shfl_xor(s, 1, 16); s += __shfl_xor(s, 2, 16); s += __shfl_xor(s, 4, 16); s += __shfl_xor(s, 8, 16); l2 = s;
    s = l3; s += __shfl_xor(s, 1, 16); s += __shfl_xor(s, 2, 16); s += __shfl_xor(s, 4, 16); s += __shfl_xor(s, 8, 16); l3 = s;
  }
  if (n == 0) {
    Lpart[wv][4 * qd + 0] = l0;
    Lpart[wv][4 * qd + 1] = l1;
    Lpart[wv][4 * qd + 2] = l2;
    Lpart[wv][4 * qd + 3] = l3;
  }
  __syncthreads();
  const float r0v = 1.0f / (Lpart[0][4 * qd + 0] + Lpart[1][4 * qd + 0] + Lpart[2][4 * qd + 0] + Lpart[3][4 * qd + 0]);
  const float r1v = 1.0f / (Lpart[0][4 * qd + 1] + Lpart[1][4 * qd + 1] + Lpart[2][4 * qd + 1] + Lpart[3][4 * qd + 1]);
  const float r2v = 1.0f / (Lpart[0][4 * qd + 2] + Lpart[1][4 * qd + 2] + Lpart[2][4 * qd + 2] + Lpart[3][4 * qd + 2]);
  const float r3v = 1.0f / (Lpart[0][4 * qd + 3] + Lpart[1][4 * qd + 3] + Lpart[2][4 * qd + 3] + Lpart[3][4 * qd + 3]);

  // ---- pass B ----
  f32x4 oc0 = {0.f, 0.f, 0.f, 0.f}, oc1 = {0.f, 0.f, 0.f, 0.f};
  const unsigned short* pVt0 = Vt + (size_t)(h * HD + n) * NN + qd * 8;  // dims 0..15 of head
  const unsigned short* pVt1 = pVt0 + (size_t)16 * NN;                   // dims 16..31
  float* pAt = attn + (size_t)h * NN * NN + (size_t)(wr0 + 4 * qd) * NN + n;

  const int cp0 = wv * 32;           // chunk-pairs [cp0, cp0+32) == chunks [c0w, c0w+64)
  short8 bh0 = *(const short8*)(pVh + (size_t)(2 * cp0) * (16 * HIDN));
  short8 bl0 = *(const short8*)(pVl + (size_t)(2 * cp0) * (16 * HIDN));
  short8 bh1 = *(const short8*)(pVh + (size_t)(2 * cp0 + 1) * (16 * HIDN));
  short8 bl1 = *(const short8*)(pVl + (size_t)(2 * cp0 + 1) * (16 * HIDN));
  short8 vb0 = *(const short8*)(pVt0 + (size_t)cp0 * 32);
  short8 vb1 = *(const short8*)(pVt1 + (size_t)cp0 * 32);

  for (int i = 0; i < 32; ++i) {
    const int cp = cp0 + i;
    const int np = cp0 + ((i < 31) ? i + 1 : 31);
    short8 bh0n = *(const short8*)(pVh + (size_t)(2 * np) * (16 * HIDN));
    short8 bl0n = *(const short8*)(pVl + (size_t)(2 * np) * (16 * HIDN));
    short8 bh1n = *(const short8*)(pVh + (size_t)(2 * np + 1) * (16 * HIDN));
    short8 bl1n = *(const short8*)(pVl + (size_t)(2 * np + 1) * (16 * HIDN));
    short8 vb0n = *(const short8*)(pVt0 + (size_t)np * 32);
    short8 vb1n = *(const short8*)(pVt1 + (size_t)np * 32);

    {   // even chunk
      const int c = 2 * cp;
      const int cl = 2 * i;                 // local mask bit index
      const size_t c0 = (size_t)c * 16;
      f32x4 acc = {0.f, 0.f, 0.f, 0.f};
      acc = __builtin_amdgcn_mfma_f32_16x16x32_bf16(a_hi, bh0, acc, 0, 0, 0);
      acc = __builtin_amdgcn_mfma_f32_16x16x32_bf16(a_lo, bh0, acc, 0, 0, 0);
      acc = __builtin_amdgcn_mfma_f32_16x16x32_bf16(a_hi, bl0, acc, 0, 0, 0);
      float p0 = ((m0 >> cl) & 1) ? __builtin_amdgcn_exp2f(acc[0]) * r0v : 0.f;
      float p1 = ((m1 >> cl) & 1) ? __builtin_amdgcn_exp2f(acc[1]) * r1v : 0.f;
      float p2 = ((m2 >> cl) & 1) ? __builtin_amdgcn_exp2f(acc[2]) * r2v : 0.f;
      float p3 = ((m3 >> cl) & 1) ? __builtin_amdgcn_exp2f(acc[3]) * r3v : 0.f;
      pAt[c0] = p0; pAt[c0 + NN] = p1; pAt[c0 + 2 * NN] = p2; pAt[c0 + 3 * NN] = p3;
      Plds[wv][4 * qd + 0][n] = f2bf(p0);
      Plds[wv][4 * qd + 1][n] = f2bf(p1);
      Plds[wv][4 * qd + 2][n] = f2bf(p2);
      Plds[wv][4 * qd + 3][n] = f2bf(p3);
    }
    {   // odd chunk
      const int c = 2 * cp + 1;
      const int cl = 2 * i + 1;
      const size_t c0 = (size_t)c * 16;
      f32x4 acc = {0.f, 0.f, 0.f, 0.f};
      acc = __builtin_amdgcn_mfma_f32_16x16x32_bf16(a_hi, bh1, acc, 0, 0, 0);
      acc = __builtin_amdgcn_mfma_f32_16x16x32_bf16(a_lo, bh1, acc, 0, 0, 0);
      acc = __builtin_amdgcn_mfma_f32_16x16x32_bf16(a_hi, bl1, acc, 0, 0, 0);
      float p0 = ((m0 >> cl) & 1) ? __builtin_amdgcn_exp2f(acc[0]) * r0v : 0.f;
      float p1 = ((m1 >> cl) & 1) ? __builtin_amdgcn_exp2f(acc[1]) * r1v : 0.f;
      float p2 = ((m2 >> cl) & 1) ? __builtin_amdgcn_exp2f(acc[2]) * r2v : 0.f;
      float p3 = ((m3 >> cl) & 1) ? __builtin_amdgcn_exp2f(acc[3]) * r3v : 0.f;
      pAt[c0] = p0; pAt[c0 + NN] = p1; pAt[c0 + 2 * NN] = p2; pAt[c0 + 3 * NN] = p3;
      Plds[wv][4 * qd + 0][16 + n] = f2bf(p0);
      Plds[wv][4 * qd + 1][16 + n] = f2bf(p1);
      Plds[wv][4 * qd + 2][16 + n] = f2bf(p2);
      Plds[wv][4 * qd + 3][16 + n] = f2bf(p3);
    }
    // LDS RAW: same-wave only (per-wave Plds slice). Compiler fence +
    // lgkmcnt(0) drain, then read A-frag.
    __asm__ volatile("" ::: "memory");
    __builtin_amdgcn_s_waitcnt(0xC07F);   // vmcnt=63, expcnt=7, lgkmcnt=0
    __asm__ volatile("" ::: "memory");
    short8 ap = *(const short8*)&Plds[wv][n][qd * 8];
    oc0 = __builtin_amdgcn_mfma_f32_16x16x32_bf16(ap, vb0, oc0, 0, 0, 0);
    oc1 = __builtin_amdgcn_mfma_f32_16x16x32_bf16(ap, vb1, oc1, 0, 0, 0);

    bh0 = bh0n; bl0 = bl0n; bh1 = bh1n; bl1 = bl1n; vb0 = vb0n; vb1 = vb1n;
  }

  // cross-wave O reduction
#pragma unroll
  for (int r = 0; r < 4; ++r) {
    Opart[wv][4 * qd + r][n]      = oc0[r];
    Opart[wv][4 * qd + r][16 + n] = oc1[r];
  }
  __syncthreads();
  {
    const int e   = tid * 2;       // 512 outputs, 2 per thread
    const int row = e >> 5;
    const int col = e & 31;
    float s0 = Opart[0][row][col]     + Opart[1][row][col]     + Opart[2][row][col]     + Opart[3][row][col];
    float s1 = Opart[0][row][col + 1] + Opart[1][row][col + 1] + Opart[2][row][col + 1] + Opart[3][row][col + 1];
    O[(size_t)(wr0 + row) * HIDN + h * HD + col]     = s0;
    O[(size_t)(wr0 + row) * HIDN + h * HD + col + 1] = s1;
  }
}

// ---------------------------------------------------------------------------
// Kernel 3: out = O @ Wo^T + bo  (fp32 vector)
// ---------------------------------------------------------------------------
__global__ __launch_bounds__(256) void mhg_oproj_kernel(
    const float* __restrict__ O,
    const float* __restrict__ wo_w, const float* __restrict__ wo_b,
    float* __restrict__ out)
{
  const int o  = threadIdx.x;
  const int r0 = blockIdx.x * 8;
  float ac[8];
#pragma unroll
  for (int r = 0; r < 8; ++r) ac[r] = 0.f;
  const float4* wo4 = (const float4*)(wo_w + (size_t)o * HIDN);
  const float* Ob = O + (size_t)r0 * HIDN;
  for (int k0 = 0; k0 < HIDN / 4; ++k0) {
    float4 w = wo4[k0];
#pragma unroll
    for (int r = 0; r < 8; ++r) {
      float4 xv = *(const float4*)(Ob + r * HIDN + k0 * 4);
      ac[r] = fmaf(xv.x, w.x, fmaf(xv.y, w.y, fmaf(xv.z, w.z, fmaf(xv.w, w.w, ac[r]))));
    }
  }
  const float b = wo_b[o];
#pragma unroll
  for (int r = 0; r < 8; ++r)
    out[(size_t)(r0 + r) * HIDN + o] = ac[r] + b;
}

extern "C" void kernel_launch(void* const* d_in, const int* in_sizes, int n_in,
                              void* d_out, int out_size, void* d_ws, size_t ws_size,
                              hipStream_t stream) {
  (void)in_sizes; (void)n_in; (void)out_size; (void)ws_size;
  const float* x    = (const float*)d_in[0];
  const int*   Adj  = (const int*)d_in[1];
  const float* wq_w = (const float*)d_in[2];
  const float* wq_b = (const float*)d_in[3];
  // d_in[4], d_in[5] = wk_w / wk_b : computed-but-unused in reference (the bug) -> skipped
  const float* wv_w = (const float*)d_in[6];
  const float* wv_b = (const float*)d_in[7];
  const float* wo_w = (const float*)d_in[8];
  const float* wo_b = (const float*)d_in[9];

  float* out  = (float*)d_out;                       // output 0: [4096,256]
  float* attn = out + (size_t)NN * HIDN;             // output 1: [8,4096,4096]

  // workspace layout (14 MB total)
  unsigned short* Qhi = (unsigned short*)d_ws;
  unsigned short* Qlo = Qhi + (size_t)NN * HIDN;
  unsigned short* Vhi = Qlo + (size_t)NN * HIDN;
  unsigned short* Vlo = Vhi + (size_t)NN * HIDN;
  unsigned short* Vt  = Vlo + (size_t)NN * HIDN;
  float*          Oacc = (float*)(Vt + (size_t)NN * HIDN);

  hipLaunchKernelGGL(mhg_qv_kernel, dim3(NN / 8), dim3(256), 0, stream,
                     x, wq_w, wq_b, wv_w, wv_b, Qhi, Qlo, Vhi, Vlo, Vt);
  hipLaunchKernelGGL(mhg_attn_kernel, dim3(NHD * (NN / 16)), dim3(256), 0, stream,
                     Adj, Qhi, Qlo, Vhi, Vlo, Vt, attn, Oacc);
  hipLaunchKernelGGL(mhg_oproj_kernel, dim3(NN / 8), dim3(256), 0, stream,
                     Oacc, wo_w, wo_b, out);
}

// Round 4
// 917.873 us; speedup vs baseline: 1.1849x; 1.1849x over previous
//
#include <hip/hip_runtime.h>
#include <hip/hip_bf16.h>
#include <stdint.h>

#define NN   4096
#define HIDN 256
#define NHD  8
#define HD   32

typedef __attribute__((ext_vector_type(8))) short short8;
typedef __attribute__((ext_vector_type(4))) float f32x4;

static __device__ __forceinline__ unsigned short f2bf(float f) {
  __hip_bfloat16 h = __float2bfloat16(f);
  return __builtin_bit_cast(unsigned short, h);
}
static __device__ __forceinline__ float bf2f(unsigned short u) {
  __hip_bfloat16 h = __builtin_bit_cast(__hip_bfloat16, u);
  return __bfloat162float(h);
}

// ---------------------------------------------------------------------------
// Kernel 1: Q = (x@Wq^T + bq) * (log2e/sqrt(32)) ; V = x@Wv^T + bv
// Written as bf16 hi/lo splits (row-major [N][256]) + single-bf16 V^T [256][N].
// fp32 vector FMA; x loads are block-uniform (scalar path), W rows per-thread.
// ---------------------------------------------------------------------------
__global__ __launch_bounds__(256) void mhg_qv_kernel(
    const float* __restrict__ x,
    const float* __restrict__ wq_w, const float* __restrict__ wq_b,
    const float* __restrict__ wv_w, const float* __restrict__ wv_b,
    unsigned short* __restrict__ Qhi, unsigned short* __restrict__ Qlo,
    unsigned short* __restrict__ Vhi, unsigned short* __restrict__ Vlo,
    unsigned short* __restrict__ Vt)
{
  const int o  = threadIdx.x;        // output column 0..255
  const int r0 = blockIdx.x * 8;     // 8 rows per block
  float aq[8], av[8];
#pragma unroll
  for (int r = 0; r < 8; ++r) { aq[r] = 0.f; av[r] = 0.f; }
  const float4* wq4 = (const float4*)(wq_w + (size_t)o * HIDN);
  const float4* wv4 = (const float4*)(wv_w + (size_t)o * HIDN);
  const float* xb = x + (size_t)r0 * HIDN;
  for (int k0 = 0; k0 < HIDN / 4; ++k0) {
    float4 wq = wq4[k0];
    float4 wv = wv4[k0];
#pragma unroll
    for (int r = 0; r < 8; ++r) {
      float4 xv = *(const float4*)(xb + r * HIDN + k0 * 4);
      aq[r] = fmaf(xv.x, wq.x, fmaf(xv.y, wq.y, fmaf(xv.z, wq.z, fmaf(xv.w, wq.w, aq[r]))));
      av[r] = fmaf(xv.x, wv.x, fmaf(xv.y, wv.y, fmaf(xv.z, wv.z, fmaf(xv.w, wv.w, av[r]))));
    }
  }
  const float bq = wq_b[o], bv = wv_b[o];
  constexpr float CS = (float)(1.4426950408889634 / 5.656854249492380195206754896838);
  alignas(16) unsigned short vt8[8];
#pragma unroll
  for (int r = 0; r < 8; ++r) {
    float qv = (aq[r] + bq) * CS;             // prescale: exp(s/sqrt(32)) == exp2(q_scaled . v)
    unsigned short qh = f2bf(qv);
    unsigned short ql = f2bf(qv - bf2f(qh));  // 2-term split: ~2^-17 relative
    float vv = av[r] + bv;
    unsigned short vh = f2bf(vv);
    unsigned short vl = f2bf(vv - bf2f(vh));
    size_t idx = (size_t)(r0 + r) * HIDN + o;
    Qhi[idx] = qh; Qlo[idx] = ql;
    Vhi[idx] = vh; Vlo[idx] = vl;
    vt8[r] = vh;                              // thread already owns column o of all 8 rows
  }
  *(uint4*)(Vt + (size_t)o * NN + r0) = *(const uint4*)vt8;  // V^T, 16B coalesced-ish store
}

// ---------------------------------------------------------------------------
// Kernel 2: fused scores -> softmax -> attn write + O accumulate.
// 4 waves (256 thr) per (head, 16-row group); wave wv owns column-chunks
// [64*wv, 64*wv+64). Pass-A l partials reduced across waves via Lpart LDS;
// pass-B O partials reduced via Opart LDS.
// launch_bounds(256,3): round-2 post-mortem -- (256,8) capped VGPRs at 64,
// allocator landed at 32 vs ~140 live (12 prefetch short8 + frags + masks),
// spilling the software pipeline to scratch. Scratch thrashed L2 (~10 MB/XCD
// vs 4 MB) -> symmetric +300 MB FETCH/WRITE leak to HBM, every pipe stalled.
// (256,3) = 170-VGPR budget: no spill, still 12 waves/CU (1.5x round-0).
// attn stores are PLAIN stores (round-1: nt stores shift traffic, don't help).
// Adjacency mask held as per-lane uint64 bitmask registers (1 bit per local
// chunk) -- each lane only ever tests its own Adj element in pass B.
// MFMA 16x16x32 bf16, K=32=head dim; hi/lo split for ~2^-17 precision.
// ---------------------------------------------------------------------------
__global__ __launch_bounds__(256, 3) void mhg_attn_kernel(
    const int* __restrict__ Adj,
    const unsigned short* __restrict__ Qhi, const unsigned short* __restrict__ Qlo,
    const unsigned short* __restrict__ Vhi, const unsigned short* __restrict__ Vlo,
    const unsigned short* __restrict__ Vt,
    float* __restrict__ attn, float* __restrict__ O)
{
  const int tid  = threadIdx.x;
  const int lane = tid & 63;
  const int wv   = tid >> 6;         // wave 0..3
  const int n    = lane & 15;        // tile column (and A-frag row m)
  const int qd   = lane >> 4;        // quad
  const int h    = blockIdx.x & (NHD - 1);   // head -> XCD-affine (bx % 8)
  const int rb   = blockIdx.x >> 3;
  const int wr0  = rb * 16;

  __shared__ __align__(16) unsigned short Plds[4][16][40];  // per-wave P tile, +8 pad
  __shared__ float Lpart[4][16];                            // per-wave row-sum partials
  __shared__ float Opart[4][16][33];                        // per-wave O partials (+1 pad)

  const size_t hoff = (size_t)h * HD + qd * 8;
  const short8 a_hi = *(const short8*)(Qhi + (size_t)(wr0 + n) * HIDN + hoff);
  const short8 a_lo = *(const short8*)(Qlo + (size_t)(wr0 + n) * HIDN + hoff);
  const unsigned short* pVh = Vhi + (size_t)n * HIDN + hoff;
  const unsigned short* pVl = Vlo + (size_t)n * HIDN + hoff;
  const size_t adjb = (size_t)(wr0 + 4 * qd) * NN + n;

  const int c0w = wv * 64;           // this wave's chunk range [c0w, c0w+64)

  float l0 = 0.f, l1 = 0.f, l2 = 0.f, l3 = 0.f;
  uint64_t m0 = 0, m1 = 0, m2 = 0, m3 = 0;   // per-lane mask bits, 1 bit/local chunk

  // ---- pass A (software-pipelined one chunk ahead) ----
  short8 bh = *(const short8*)(pVh + (size_t)c0w * (16 * HIDN));
  short8 bl = *(const short8*)(pVl + (size_t)c0w * (16 * HIDN));
  size_t ab0 = adjb + (size_t)c0w * 16;
  int a0 = Adj[ab0], a1 = Adj[ab0 + NN], a2 = Adj[ab0 + 2 * NN], a3 = Adj[ab0 + 3 * NN];

  for (int cc = 0; cc < 64; ++cc) {
    const int cn = c0w + ((cc < 63) ? cc + 1 : 63);
    short8 bhn = *(const short8*)(pVh + (size_t)cn * (16 * HIDN));
    short8 bln = *(const short8*)(pVl + (size_t)cn * (16 * HIDN));
    const size_t ab = adjb + (size_t)cn * 16;
    int a0n = Adj[ab], a1n = Adj[ab + NN], a2n = Adj[ab + 2 * NN], a3n = Adj[ab + 3 * NN];

    f32x4 acc = {0.f, 0.f, 0.f, 0.f};
    acc = __builtin_amdgcn_mfma_f32_16x16x32_bf16(a_hi, bh, acc, 0, 0, 0);
    acc = __builtin_amdgcn_mfma_f32_16x16x32_bf16(a_lo, bh, acc, 0, 0, 0);
    acc = __builtin_amdgcn_mfma_f32_16x16x32_bf16(a_hi, bl, acc, 0, 0, 0);

    m0 |= (uint64_t)(a0 != 0) << cc;
    m1 |= (uint64_t)(a1 != 0) << cc;
    m2 |= (uint64_t)(a2 != 0) << cc;
    m3 |= (uint64_t)(a3 != 0) << cc;

    l0 += a0 ? __builtin_amdgcn_exp2f(acc[0]) : 0.f;
    l1 += a1 ? __builtin_amdgcn_exp2f(acc[1]) : 0.f;
    l2 += a2 ? __builtin_amdgcn_exp2f(acc[2]) : 0.f;
    l3 += a3 ? __builtin_amdgcn_exp2f(acc[3]) : 0.f;

    bh = bhn; bl = bln; a0 = a0n; a1 = a1n; a2 = a2n; a3 = a3n;
  }

  // quad-local butterfly (width 16), then cross-wave sum via LDS
  {
    float s;
    s = l0; s += __shfl_xor(s, 1, 16); s += __shfl_xor(s, 2, 16); s += __shfl_xor(s, 4, 16); s += __shfl_xor(s, 8, 16); l0 = s;
    s = l1; s += __shfl_xor(s, 1, 16); s += __shfl_xor(s, 2, 16); s += __shfl_xor(s, 4, 16); s += __shfl_xor(s, 8, 16); l1 = s;
    s = l2; s += __shfl_xor(s, 1, 16); s += __shfl_xor(s, 2, 16); s += __shfl_xor(s, 4, 16); s += __shfl_xor(s, 8, 16); l2 = s;
    s = l3; s += __shfl_xor(s, 1, 16); s += __shfl_xor(s, 2, 16); s += __shfl_xor(s, 4, 16); s += __shfl_xor(s, 8, 16); l3 = s;
  }
  if (n == 0) {
    Lpart[wv][4 * qd + 0] = l0;
    Lpart[wv][4 * qd + 1] = l1;
    Lpart[wv][4 * qd + 2] = l2;
    Lpart[wv][4 * qd + 3] = l3;
  }
  __syncthreads();
  const float r0v = 1.0f / (Lpart[0][4 * qd + 0] + Lpart[1][4 * qd + 0] + Lpart[2][4 * qd + 0] + Lpart[3][4 * qd + 0]);
  const float r1v = 1.0f / (Lpart[0][4 * qd + 1] + Lpart[1][4 * qd + 1] + Lpart[2][4 * qd + 1] + Lpart[3][4 * qd + 1]);
  const float r2v = 1.0f / (Lpart[0][4 * qd + 2] + Lpart[1][4 * qd + 2] + Lpart[2][4 * qd + 2] + Lpart[3][4 * qd + 2]);
  const float r3v = 1.0f / (Lpart[0][4 * qd + 3] + Lpart[1][4 * qd + 3] + Lpart[2][4 * qd + 3] + Lpart[3][4 * qd + 3]);

  // ---- pass B ----
  f32x4 oc0 = {0.f, 0.f, 0.f, 0.f}, oc1 = {0.f, 0.f, 0.f, 0.f};
  const unsigned short* pVt0 = Vt + (size_t)(h * HD + n) * NN + qd * 8;  // dims 0..15 of head
  const unsigned short* pVt1 = pVt0 + (size_t)16 * NN;                   // dims 16..31
  float* pAt = attn + (size_t)h * NN * NN + (size_t)(wr0 + 4 * qd) * NN + n;

  const int cp0 = wv * 32;           // chunk-pairs [cp0, cp0+32) == chunks [c0w, c0w+64)
  short8 bh0 = *(const short8*)(pVh + (size_t)(2 * cp0) * (16 * HIDN));
  short8 bl0 = *(const short8*)(pVl + (size_t)(2 * cp0) * (16 * HIDN));
  short8 bh1 = *(const short8*)(pVh + (size_t)(2 * cp0 + 1) * (16 * HIDN));
  short8 bl1 = *(const short8*)(pVl + (size_t)(2 * cp0 + 1) * (16 * HIDN));
  short8 vb0 = *(const short8*)(pVt0 + (size_t)cp0 * 32);
  short8 vb1 = *(const short8*)(pVt1 + (size_t)cp0 * 32);

  for (int i = 0; i < 32; ++i) {
    const int cp = cp0 + i;
    const int np = cp0 + ((i < 31) ? i + 1 : 31);
    short8 bh0n = *(const short8*)(pVh + (size_t)(2 * np) * (16 * HIDN));
    short8 bl0n = *(const short8*)(pVl + (size_t)(2 * np) * (16 * HIDN));
    short8 bh1n = *(const short8*)(pVh + (size_t)(2 * np + 1) * (16 * HIDN));
    short8 bl1n = *(const short8*)(pVl + (size_t)(2 * np + 1) * (16 * HIDN));
    short8 vb0n = *(const short8*)(pVt0 + (size_t)np * 32);
    short8 vb1n = *(const short8*)(pVt1 + (size_t)np * 32);

    {   // even chunk
      const int c = 2 * cp;
      const int cl = 2 * i;                 // local mask bit index
      const size_t c0 = (size_t)c * 16;
      f32x4 acc = {0.f, 0.f, 0.f, 0.f};
      acc = __builtin_amdgcn_mfma_f32_16x16x32_bf16(a_hi, bh0, acc, 0, 0, 0);
      acc = __builtin_amdgcn_mfma_f32_16x16x32_bf16(a_lo, bh0, acc, 0, 0, 0);
      acc = __builtin_amdgcn_mfma_f32_16x16x32_bf16(a_hi, bl0, acc, 0, 0, 0);
      float p0 = ((m0 >> cl) & 1) ? __builtin_amdgcn_exp2f(acc[0]) * r0v : 0.f;
      float p1 = ((m1 >> cl) & 1) ? __builtin_amdgcn_exp2f(acc[1]) * r1v : 0.f;
      float p2 = ((m2 >> cl) & 1) ? __builtin_amdgcn_exp2f(acc[2]) * r2v : 0.f;
      float p3 = ((m3 >> cl) & 1) ? __builtin_amdgcn_exp2f(acc[3]) * r3v : 0.f;
      pAt[c0] = p0; pAt[c0 + NN] = p1; pAt[c0 + 2 * NN] = p2; pAt[c0 + 3 * NN] = p3;
      Plds[wv][4 * qd + 0][n] = f2bf(p0);
      Plds[wv][4 * qd + 1][n] = f2bf(p1);
      Plds[wv][4 * qd + 2][n] = f2bf(p2);
      Plds[wv][4 * qd + 3][n] = f2bf(p3);
    }
    {   // odd chunk
      const int c = 2 * cp + 1;
      const int cl = 2 * i + 1;
      const size_t c0 = (size_t)c * 16;
      f32x4 acc = {0.f, 0.f, 0.f, 0.f};
      acc = __builtin_amdgcn_mfma_f32_16x16x32_bf16(a_hi, bh1, acc, 0, 0, 0);
      acc = __builtin_amdgcn_mfma_f32_16x16x32_bf16(a_lo, bh1, acc, 0, 0, 0);
      acc = __builtin_amdgcn_mfma_f32_16x16x32_bf16(a_hi, bl1, acc, 0, 0, 0);
      float p0 = ((m0 >> cl) & 1) ? __builtin_amdgcn_exp2f(acc[0]) * r0v : 0.f;
      float p1 = ((m1 >> cl) & 1) ? __builtin_amdgcn_exp2f(acc[1]) * r1v : 0.f;
      float p2 = ((m2 >> cl) & 1) ? __builtin_amdgcn_exp2f(acc[2]) * r2v : 0.f;
      float p3 = ((m3 >> cl) & 1) ? __builtin_amdgcn_exp2f(acc[3]) * r3v : 0.f;
      pAt[c0] = p0; pAt[c0 + NN] = p1; pAt[c0 + 2 * NN] = p2; pAt[c0 + 3 * NN] = p3;
      Plds[wv][4 * qd + 0][16 + n] = f2bf(p0);
      Plds[wv][4 * qd + 1][16 + n] = f2bf(p1);
      Plds[wv][4 * qd + 2][16 + n] = f2bf(p2);
      Plds[wv][4 * qd + 3][16 + n] = f2bf(p3);
    }
    // LDS RAW: same-wave only (per-wave Plds slice). Compiler fence +
    // lgkmcnt(0) drain, then read A-frag.
    __asm__ volatile("" ::: "memory");
    __builtin_amdgcn_s_waitcnt(0xC07F);   // vmcnt=63, expcnt=7, lgkmcnt=0
    __asm__ volatile("" ::: "memory");
    short8 ap = *(const short8*)&Plds[wv][n][qd * 8];
    oc0 = __builtin_amdgcn_mfma_f32_16x16x32_bf16(ap, vb0, oc0, 0, 0, 0);
    oc1 = __builtin_amdgcn_mfma_f32_16x16x32_bf16(ap, vb1, oc1, 0, 0, 0);

    bh0 = bh0n; bl0 = bl0n; bh1 = bh1n; bl1 = bl1n; vb0 = vb0n; vb1 = vb1n;
  }

  // cross-wave O reduction
#pragma unroll
  for (int r = 0; r < 4; ++r) {
    Opart[wv][4 * qd + r][n]      = oc0[r];
    Opart[wv][4 * qd + r][16 + n] = oc1[r];
  }
  __syncthreads();
  {
    const int e   = tid * 2;       // 512 outputs, 2 per thread
    const int row = e >> 5;
    const int col = e & 31;
    float s0 = Opart[0][row][col]     + Opart[1][row][col]     + Opart[2][row][col]     + Opart[3][row][col];
    float s1 = Opart[0][row][col + 1] + Opart[1][row][col + 1] + Opart[2][row][col + 1] + Opart[3][row][col + 1];
    O[(size_t)(wr0 + row) * HIDN + h * HD + col]     = s0;
    O[(size_t)(wr0 + row) * HIDN + h * HD + col + 1] = s1;
  }
}

// ---------------------------------------------------------------------------
// Kernel 3: out = O @ Wo^T + bo  (fp32 vector)
// ---------------------------------------------------------------------------
__global__ __launch_bounds__(256) void mhg_oproj_kernel(
    const float* __restrict__ O,
    const float* __restrict__ wo_w, const float* __restrict__ wo_b,
    float* __restrict__ out)
{
  const int o  = threadIdx.x;
  const int r0 = blockIdx.x * 8;
  float ac[8];
#pragma unroll
  for (int r = 0; r < 8; ++r) ac[r] = 0.f;
  const float4* wo4 = (const float4*)(wo_w + (size_t)o * HIDN);
  const float* Ob = O + (size_t)r0 * HIDN;
  for (int k0 = 0; k0 < HIDN / 4; ++k0) {
    float4 w = wo4[k0];
#pragma unroll
    for (int r = 0; r < 8; ++r) {
      float4 xv = *(const float4*)(Ob + r * HIDN + k0 * 4);
      ac[r] = fmaf(xv.x, w.x, fmaf(xv.y, w.y, fmaf(xv.z, w.z, fmaf(xv.w, w.w, ac[r]))));
    }
  }
  const float b = wo_b[o];
#pragma unroll
  for (int r = 0; r < 8; ++r)
    out[(size_t)(r0 + r) * HIDN + o] = ac[r] + b;
}

extern "C" void kernel_launch(void* const* d_in, const int* in_sizes, int n_in,
                              void* d_out, int out_size, void* d_ws, size_t ws_size,
                              hipStream_t stream) {
  (void)in_sizes; (void)n_in; (void)out_size; (void)ws_size;
  const float* x    = (const float*)d_in[0];
  const int*   Adj  = (const int*)d_in[1];
  const float* wq_w = (const float*)d_in[2];
  const float* wq_b = (const float*)d_in[3];
  // d_in[4], d_in[5] = wk_w / wk_b : computed-but-unused in reference (the bug) -> skipped
  const float* wv_w = (const float*)d_in[6];
  const float* wv_b = (const float*)d_in[7];
  const float* wo_w = (const float*)d_in[8];
  const float* wo_b = (const float*)d_in[9];

  float* out  = (float*)d_out;                       // output 0: [4096,256]
  float* attn = out + (size_t)NN * HIDN;             // output 1: [8,4096,4096]

  // workspace layout (14 MB total)
  unsigned short* Qhi = (unsigned short*)d_ws;
  unsigned short* Qlo = Qhi + (size_t)NN * HIDN;
  unsigned short* Vhi = Qlo + (size_t)NN * HIDN;
  unsigned short* Vlo = Vhi + (size_t)NN * HIDN;
  unsigned short* Vt  = Vlo + (size_t)NN * HIDN;
  float*          Oacc = (float*)(Vt + (size_t)NN * HIDN);

  hipLaunchKernelGGL(mhg_qv_kernel, dim3(NN / 8), dim3(256), 0, stream,
                     x, wq_w, wq_b, wv_w, wv_b, Qhi, Qlo, Vhi, Vlo, Vt);
  hipLaunchKernelGGL(mhg_attn_kernel, dim3(NHD * (NN / 16)), dim3(256), 0, stream,
                     Adj, Qhi, Qlo, Vhi, Vlo, Vt, attn, Oacc);
  hipLaunchKernelGGL(mhg_oproj_kernel, dim3(NN / 8), dim3(256), 0, stream,
                     Oacc, wo_w, wo_b, out);
}